// Round 1
// 1321.059 us; speedup vs baseline: 1.0363x; 1.0363x over previous
//
#include <hip/hip_runtime.h>

using short8  = __attribute__((ext_vector_type(8))) short;
using floatx4 = __attribute__((ext_vector_type(4))) float;

#define D_MODEL 512
#define N_HEAD 8
#define HEAD_DIM 64
#define B_ 8
#define T_ 384
#define N_SLOTS 3072   // B_*T_
#define N_TOK 2048

__device__ __forceinline__ float bf2f(ushort u) {
  union { uint u32; float f; } c; c.u32 = ((uint)u) << 16; return c.f;
}
__device__ __forceinline__ float2 bf2x2(uint u) {
  union { uint u32; float f; } lo, hi;
  lo.u32 = u << 16; hi.u32 = u & 0xffff0000u;
  float2 r; r.x = lo.f; r.y = hi.f; return r;
}
__device__ __forceinline__ ushort f2bf(float f) {
  union { float f; uint u; } c; c.f = f;
  uint x = c.u;
  x += 0x7fffu + ((x >> 16) & 1u);
  return (ushort)(x >> 16);
}

// Classify the dtype of x: bf16 data -> even-indexed 16b words have sane bf16
// exponents (~100%); fp32 data -> those words are mantissa bits (~24% sane).
// flag[0] = 1 means fp32, 0 means bf16. Deterministic every call.
__global__ __launch_bounds__(256) void probe_dtype(const ushort* __restrict__ x,
                                                   int* __restrict__ flag) {
  __shared__ int cnt;
  if (threadIdx.x == 0) cnt = 0;
  __syncthreads();
  int c = 0;
  for (int i = threadIdx.x; i < 1024; i += 256) {
    ushort w = x[2 * i];
    int e = (w >> 7) & 0xFF;
    if (e >= 100 && e <= 160) c++;
  }
  atomicAdd(&cnt, c);
  __syncthreads();
  if (threadIdx.x == 0) flag[0] = (cnt < 700) ? 1 : 0;
}

__device__ __forceinline__ void load8(const void* p, size_t off, int isF32, float* av) {
  if (isF32) {
    const float* fp = (const float*)p + off;
    float4 a = *(const float4*)fp;
    float4 b = *(const float4*)(fp + 4);
    av[0]=a.x; av[1]=a.y; av[2]=a.z; av[3]=a.w;
    av[4]=b.x; av[5]=b.y; av[6]=b.z; av[7]=b.w;
  } else {
    const ushort* up = (const ushort*)p + off;
    uint4 w = *(const uint4*)up;
    float2 p0 = bf2x2(w.x), p1 = bf2x2(w.y), p2 = bf2x2(w.z), p3 = bf2x2(w.w);
    av[0]=p0.x; av[1]=p0.y; av[2]=p1.x; av[3]=p1.y;
    av[4]=p2.x; av[5]=p2.y; av[6]=p3.x; av[7]=p3.y;
  }
}

__device__ __forceinline__ void pack_hl(const float* av, uint4& ph, uint4& pl) {
  ushort hh[8], ll[8];
  #pragma unroll
  for (int j = 0; j < 8; j++) {
    hh[j] = f2bf(av[j]);
    ll[j] = f2bf(av[j] - bf2f(hh[j]));   // exactly 0 when av is bf16-valued
  }
  ph.x = (uint)hh[0] | ((uint)hh[1] << 16);
  ph.y = (uint)hh[2] | ((uint)hh[3] << 16);
  ph.z = (uint)hh[4] | ((uint)hh[5] << 16);
  ph.w = (uint)hh[6] | ((uint)hh[7] << 16);
  pl.x = (uint)ll[0] | ((uint)ll[1] << 16);
  pl.y = (uint)ll[2] | ((uint)ll[3] << 16);
  pl.z = (uint)ll[4] | ((uint)ll[5] << 16);
  pl.w = (uint)ll[6] | ((uint)ll[7] << 16);
}

// C = A(gathered rows) @ W^T + bias, computed via hi/lo bf16 split (3 MFMAs)
// so both bf16 and fp32 inputs are handled ~fp32-accurately.
// A_WS: A is a fp32 workspace array. MODE 0: store fp32 to q/k/v ws layout
// [B][H][T][64]; MODE 1: store to d_out (dtype per flag), row-major [M][512].
template<int A_WS, int MODE>
__global__ __launch_bounds__(256) void gemm_bt(
    const void* __restrict__ Av, const int* __restrict__ gidx,
    const void* __restrict__ Wv, const void* __restrict__ biasv,
    void* __restrict__ outv, const int* __restrict__ flag)
{
  const int f32m = flag[0];
  __shared__ __align__(16) ushort Ash[64][40], Asl[64][40];
  __shared__ __align__(16) ushort Bsh[64][40], Bsl[64][40];
  const int m0 = blockIdx.x * 64;
  const int n0 = blockIdx.y * 64;
  const int tid = threadIdx.x;
  const int wave = tid >> 6, lane = tid & 63;
  const int quad = lane >> 4, l16 = lane & 15;
  const int srow = tid >> 2, sseg = tid & 3;

  const int arow = m0 + srow;
  const int atok = gidx[arow];
  const int brow = n0 + srow;

  floatx4 acc[4];
  #pragma unroll
  for (int i = 0; i < 4; i++) acc[i] = (floatx4){0.f, 0.f, 0.f, 0.f};

  // register double-buffer: issue next k-tile's global loads under the MFMAs
  float avA[8], avB[8];
  load8(Av, (size_t)atok * D_MODEL + sseg * 8, A_WS ? 1 : f32m, avA);
  load8(Wv, (size_t)brow * D_MODEL + sseg * 8, f32m, avB);

  for (int k0 = 0; k0 < D_MODEL; k0 += 32) {
    uint4 ph, pl;
    pack_hl(avA, ph, pl);
    *(uint4*)&Ash[srow][sseg * 8] = ph;
    *(uint4*)&Asl[srow][sseg * 8] = pl;
    pack_hl(avB, ph, pl);
    *(uint4*)&Bsh[srow][sseg * 8] = ph;
    *(uint4*)&Bsl[srow][sseg * 8] = pl;
    __syncthreads();

    float nvA[8], nvB[8];
    if (k0 + 32 < D_MODEL) {
      load8(Av, (size_t)atok * D_MODEL + k0 + 32 + sseg * 8, A_WS ? 1 : f32m, nvA);
      load8(Wv, (size_t)brow * D_MODEL + k0 + 32 + sseg * 8, f32m, nvB);
    }

    short8 ah = *(const short8*)&Ash[wave * 16 + l16][quad * 8];
    short8 al = *(const short8*)&Asl[wave * 16 + l16][quad * 8];
    #pragma unroll
    for (int cg = 0; cg < 4; cg++) {
      short8 bh = *(const short8*)&Bsh[cg * 16 + l16][quad * 8];
      short8 bl = *(const short8*)&Bsl[cg * 16 + l16][quad * 8];
      acc[cg] = __builtin_amdgcn_mfma_f32_16x16x32_bf16(ah, bh, acc[cg], 0, 0, 0);
      acc[cg] = __builtin_amdgcn_mfma_f32_16x16x32_bf16(ah, bl, acc[cg], 0, 0, 0);
      acc[cg] = __builtin_amdgcn_mfma_f32_16x16x32_bf16(al, bh, acc[cg], 0, 0, 0);
    }
    __syncthreads();

    #pragma unroll
    for (int j = 0; j < 8; j++) { avA[j] = nvA[j]; avB[j] = nvB[j]; }
  }

  #pragma unroll
  for (int cg = 0; cg < 4; cg++) {
    const int col = n0 + cg * 16 + l16;
    const float bv = f32m ? ((const float*)biasv)[col] : bf2f(((const ushort*)biasv)[col]);
    #pragma unroll
    for (int r = 0; r < 4; r++) {
      const int row = m0 + wave * 16 + quad * 4 + r;
      const float val = acc[cg][r] + bv;
      if (MODE == 0) {
        const int bb = row / T_;
        const int t = row - bb * T_;
        const int hh = col >> 6;
        const int dh = col & 63;
        ((float*)outv)[(((size_t)(bb * N_HEAD + hh) * T_ + t) * HEAD_DIM) + dh] = val;
      } else {
        if (f32m) ((float*)outv)[(size_t)row * D_MODEL + col] = val;
        else      ((ushort*)outv)[(size_t)row * D_MODEL + col] = f2bf(val);
      }
    }
  }
}

// one (q_row, t) dot product over d=64, with 4 independent partial accumulators
// to break the serial FMA chain and let loads issue ahead.
__device__ __forceinline__ float dot64(const float* kb, const void* rv, size_t ro,
                                       int f32m, const float* qrow) {
  float a0 = 0.f, a1 = 0.f, a2 = 0.f, a3 = 0.f;
  const float4* kp = (const float4*)kb;
  if (f32m) {
    const float4* rp = (const float4*)((const float*)rv + ro);
    #pragma unroll
    for (int c = 0; c < 16; c += 4) {
      const float4 k0 = kp[c],   r0 = rp[c];
      const float4 k1 = kp[c+1], r1 = rp[c+1];
      const float4 k2 = kp[c+2], r2 = rp[c+2];
      const float4 k3 = kp[c+3], r3 = rp[c+3];
      const float4 q0 = *(const float4*)(qrow + c * 4);
      const float4 q1 = *(const float4*)(qrow + c * 4 + 4);
      const float4 q2 = *(const float4*)(qrow + c * 4 + 8);
      const float4 q3 = *(const float4*)(qrow + c * 4 + 12);
      a0 = fmaf(q0.x, k0.x + r0.x, a0); a0 = fmaf(q0.y, k0.y + r0.y, a0);
      a0 = fmaf(q0.z, k0.z + r0.z, a0); a0 = fmaf(q0.w, k0.w + r0.w, a0);
      a1 = fmaf(q1.x, k1.x + r1.x, a1); a1 = fmaf(q1.y, k1.y + r1.y, a1);
      a1 = fmaf(q1.z, k1.z + r1.z, a1); a1 = fmaf(q1.w, k1.w + r1.w, a1);
      a2 = fmaf(q2.x, k2.x + r2.x, a2); a2 = fmaf(q2.y, k2.y + r2.y, a2);
      a2 = fmaf(q2.z, k2.z + r2.z, a2); a2 = fmaf(q2.w, k2.w + r2.w, a2);
      a3 = fmaf(q3.x, k3.x + r3.x, a3); a3 = fmaf(q3.y, k3.y + r3.y, a3);
      a3 = fmaf(q3.z, k3.z + r3.z, a3); a3 = fmaf(q3.w, k3.w + r3.w, a3);
    }
  } else {
    const uint4* rp = (const uint4*)((const ushort*)rv + ro);
    #pragma unroll
    for (int c = 0; c < 8; c += 2) {
      const uint4 rwa = rp[c];
      const uint4 rwb = rp[c + 1];
      const float4 k0 = kp[2*c],   k1 = kp[2*c+1];
      const float4 k2 = kp[2*c+2], k3 = kp[2*c+3];
      const float4 q0 = *(const float4*)(qrow + c * 8);
      const float4 q1 = *(const float4*)(qrow + c * 8 + 4);
      const float4 q2 = *(const float4*)(qrow + c * 8 + 8);
      const float4 q3 = *(const float4*)(qrow + c * 8 + 12);
      const float2 r0 = bf2x2(rwa.x), r1 = bf2x2(rwa.y);
      const float2 r2 = bf2x2(rwa.z), r3 = bf2x2(rwa.w);
      const float2 r4 = bf2x2(rwb.x), r5 = bf2x2(rwb.y);
      const float2 r6 = bf2x2(rwb.z), r7 = bf2x2(rwb.w);
      a0 = fmaf(q0.x, k0.x + r0.x, a0); a0 = fmaf(q0.y, k0.y + r0.y, a0);
      a0 = fmaf(q0.z, k0.z + r1.x, a0); a0 = fmaf(q0.w, k0.w + r1.y, a0);
      a1 = fmaf(q1.x, k1.x + r2.x, a1); a1 = fmaf(q1.y, k1.y + r2.y, a1);
      a1 = fmaf(q1.z, k1.z + r3.x, a1); a1 = fmaf(q1.w, k1.w + r3.y, a1);
      a2 = fmaf(q2.x, k2.x + r4.x, a2); a2 = fmaf(q2.y, k2.y + r4.y, a2);
      a2 = fmaf(q2.z, k2.z + r5.x, a2); a2 = fmaf(q2.w, k2.w + r5.y, a2);
      a3 = fmaf(q3.x, k3.x + r6.x, a3); a3 = fmaf(q3.y, k3.y + r6.y, a3);
      a3 = fmaf(q3.z, k3.z + r7.x, a3); a3 = fmaf(q3.w, k3.w + r7.y, a3);
    }
  }
  return (a0 + a1) + (a2 + a3);
}

// One block per (b, s). 256 threads: 8 head-groups of 32 lanes.
// q/k/v/y are fp32 workspace; relkeys/relvals dtype per flag.
__global__ __launch_bounds__(256, 4) void attn_kernel(
    const float* __restrict__ q, const float* __restrict__ k,
    const float* __restrict__ v, const void* __restrict__ rkv,
    const void* __restrict__ rvv, const int* __restrict__ batch,
    float* __restrict__ y, const int* __restrict__ flag)
{
  const int f32m = flag[0];
  const int s = blockIdx.x;
  const int b = blockIdx.y;
  const int tid = threadIdx.x;

  __shared__ __align__(16) float qf[N_HEAD][HEAD_DIM];   // 2 KB
  __shared__ __align__(16) float probs[N_HEAD][T_];      // 12 KB
  __shared__ int   bt[T_];                               // 1.5 KB
  __shared__ float rsum[N_HEAD];

  for (int i = tid; i < D_MODEL; i += 256) {
    const int h = i >> 6, d = i & 63;
    qf[h][d] = q[(((size_t)(b * N_HEAD + h) * T_ + s) * HEAD_DIM) + d];
  }
  for (int i = tid; i < T_; i += 256) bt[i] = batch[b * T_ + i];
  __syncthreads();

  const int myb = bt[s];
  const int h = tid >> 5, tl = tid & 31;
  const float scale = 0.125f;

  const float* kbase = k + ((size_t)(b * N_HEAD + h) * T_) * HEAD_DIM;
  const size_t roff = ((size_t)(b * T_ + s)) * T_ * HEAD_DIM;

  // ---------------- score pass: two independent t-streams per iteration ----
  float sc[12];
  #pragma unroll
  for (int i = 0; i < 6; i++) {
    const int ta = i * 32 + tl;
    const int tb = ta + 192;
    const float sa = dot64(kbase + (size_t)ta * HEAD_DIM, rkv,
                           roff + (size_t)ta * HEAD_DIM, f32m, &qf[h][0]);
    const float sb = dot64(kbase + (size_t)tb * HEAD_DIM, rkv,
                           roff + (size_t)tb * HEAD_DIM, f32m, &qf[h][0]);
    sc[i]     = (bt[ta] == myb) ? sa * scale : -1e9f;
    sc[i + 6] = (bt[tb] == myb) ? sb * scale : -1e9f;
  }

  // softmax over the 32-lane head group (each lane holds 12 t-values)
  float m = sc[0];
  #pragma unroll
  for (int i = 1; i < 12; i++) m = fmaxf(m, sc[i]);
  #pragma unroll
  for (int off = 1; off < 32; off <<= 1) m = fmaxf(m, __shfl_xor(m, off, 64));
  float sum = 0.f;
  #pragma unroll
  for (int i = 0; i < 12; i++) { sc[i] = __expf(sc[i] - m); sum += sc[i]; }
  #pragma unroll
  for (int off = 1; off < 32; off <<= 1) sum += __shfl_xor(sum, off, 64);
  #pragma unroll
  for (int i = 0; i < 6; i++) {
    probs[h][i * 32 + tl]       = sc[i];
    probs[h][(i + 6) * 32 + tl] = sc[i + 6];
  }
  if (tl == 0) rsum[h] = 1.f / sum;
  __syncthreads();

  // ---------------- y pass: thread = (h, d-octet, t-quarter) ---------------
  // 8 d-groups x 4 t-quarters per head: 96 iterations, 48 B loaded per iter,
  // partials combined across the 4 t-quarters with shfl_xor.
  const int dq = tl & 7, tq = tl >> 3;
  const int d0 = dq * 8;
  const int t0 = tq * 96;
  const float* vp = v + ((size_t)(b * N_HEAD + h) * T_) * HEAD_DIM + d0;

  float ac[8];
  #pragma unroll
  for (int j = 0; j < 8; j++) ac[j] = 0.f;

  if (f32m) {
    const float* rvp = (const float*)rvv + roff + d0;
    #pragma unroll 4
    for (int t = t0; t < t0 + 96; t++) {
      const float p = probs[h][t];
      const float4 v0 = *(const float4*)(vp + (size_t)t * HEAD_DIM);
      const float4 v1 = *(const float4*)(vp + (size_t)t * HEAD_DIM + 4);
      const float4 r0 = *(const float4*)(rvp + (size_t)t * HEAD_DIM);
      const float4 r1 = *(const float4*)(rvp + (size_t)t * HEAD_DIM + 4);
      ac[0] = fmaf(p, v0.x + r0.x, ac[0]);
      ac[1] = fmaf(p, v0.y + r0.y, ac[1]);
      ac[2] = fmaf(p, v0.z + r0.z, ac[2]);
      ac[3] = fmaf(p, v0.w + r0.w, ac[3]);
      ac[4] = fmaf(p, v1.x + r1.x, ac[4]);
      ac[5] = fmaf(p, v1.y + r1.y, ac[5]);
      ac[6] = fmaf(p, v1.z + r1.z, ac[6]);
      ac[7] = fmaf(p, v1.w + r1.w, ac[7]);
    }
  } else {
    const ushort* rvp = (const ushort*)rvv + roff + d0;
    #pragma unroll 4
    for (int t = t0; t < t0 + 96; t++) {
      const float p = probs[h][t];
      const float4 v0 = *(const float4*)(vp + (size_t)t * HEAD_DIM);
      const float4 v1 = *(const float4*)(vp + (size_t)t * HEAD_DIM + 4);
      const uint4 rw = *(const uint4*)(rvp + (size_t)t * HEAD_DIM);
      const float2 r0 = bf2x2(rw.x), r1 = bf2x2(rw.y);
      const float2 r2 = bf2x2(rw.z), r3 = bf2x2(rw.w);
      ac[0] = fmaf(p, v0.x + r0.x, ac[0]);
      ac[1] = fmaf(p, v0.y + r0.y, ac[1]);
      ac[2] = fmaf(p, v0.z + r1.x, ac[2]);
      ac[3] = fmaf(p, v0.w + r1.y, ac[3]);
      ac[4] = fmaf(p, v1.x + r2.x, ac[4]);
      ac[5] = fmaf(p, v1.y + r2.y, ac[5]);
      ac[6] = fmaf(p, v1.z + r3.x, ac[6]);
      ac[7] = fmaf(p, v1.w + r3.y, ac[7]);
    }
  }

  // combine the 4 t-quarter partials (tq encoded in lane bits 3..4)
  #pragma unroll
  for (int j = 0; j < 8; j++) {
    ac[j] += __shfl_xor(ac[j], 8, 64);
    ac[j] += __shfl_xor(ac[j], 16, 64);
  }

  if (tq == 0) {
    const float rs = rsum[h];
    float4 o0, o1;
    o0.x = ac[0] * rs; o0.y = ac[1] * rs; o0.z = ac[2] * rs; o0.w = ac[3] * rs;
    o1.x = ac[4] * rs; o1.y = ac[5] * rs; o1.z = ac[6] * rs; o1.w = ac[7] * rs;
    float* yp = y + ((size_t)(b * T_ + s)) * D_MODEL + h * HEAD_DIM + d0;
    *(float4*)yp = o0;
    *(float4*)(yp + 4) = o1;
  }
}

extern "C" void kernel_launch(void* const* d_in, const int* in_sizes, int n_in,
                              void* d_out, int out_size, void* d_ws, size_t ws_size,
                              hipStream_t stream) {
  const void* x    = d_in[0];
  const void* relk = d_in[1];
  const void* relv = d_in[2];
  const void* Wq   = d_in[3];
  const void* bq   = d_in[4];
  const void* Wk   = d_in[5];
  const void* bk   = d_in[6];
  const void* Wv   = d_in[7];
  const void* bv   = d_in[8];
  const void* Wp   = d_in[9];
  const void* bp   = d_in[10];
  const int* pidx   = (const int*)d_in[11];
  const int* pbatch = (const int*)d_in[12];
  const int* pinv   = (const int*)d_in[13];

  float* ws = (float*)d_ws;
  const size_t SE = (size_t)N_SLOTS * D_MODEL;  // 1,572,864 floats (6.29 MB)
  float* qb = ws;
  float* kb = ws + SE;
  float* vb = ws + 2 * SE;
  float* yb = ws + 3 * SE;
  int* flag = (int*)((char*)d_ws + 28u * 1024u * 1024u);  // past 25.2 MB of tensors

  probe_dtype<<<1, 256, 0, stream>>>((const ushort*)x, flag);
  gemm_bt<0, 0><<<dim3(48, 8), 256, 0, stream>>>(x, pidx, Wq, bq, qb, flag);
  gemm_bt<0, 0><<<dim3(48, 8), 256, 0, stream>>>(x, pidx, Wk, bk, kb, flag);
  gemm_bt<0, 0><<<dim3(48, 8), 256, 0, stream>>>(x, pidx, Wv, bv, vb, flag);
  attn_kernel<<<dim3(T_, B_), 256, 0, stream>>>(qb, kb, vb, relk, relv, pbatch, yb, flag);
  gemm_bt<1, 1><<<dim3(32, 8), 256, 0, stream>>>(yb, pinv, Wp, bp, d_out, flag);
}